// Round 5
// baseline (147.261 us; speedup 1.0000x reference)
//
#include <hip/hip_runtime.h>
#include <hip/hip_bf16.h>

#define HH 512
#define WW 512
#define NJ 250
#define NBINS 8192
#define NPAIR 31125   // 250*249/2

#define HBLK 32
#define HTHR 1024
#define BINS_PER_T (NBINS / HTHR)   // 8
#define CBLK 2048
#define CTHR 256
#define CWAVES (CBLK * CTHR / 64)

// ws layout:
//   u64 hist[HBLK][NBINS]   @ 0      (2 MB) — fully overwritten each launch (plain
//                                     agent stores), NO poison arithmetic needed
//   f32 max20               @ 2 MB
//   u32 sentinel            @ 2 MB + 64   <- NEVER written: holds poison pattern
//   u32 barrier             @ 2 MB + 128  <- fetch_add'ed; poison-initialized
// packet = (1<<44) | round(v*2^24): cnt in [63:44], fixed-point sum in [43:0].
// merged-over-32-blocks packet still fits: cnt <= 2^18 < 2^20, sum <= 2^42 < 2^44.
// barrier counter: init == poison u32; "last" block sees (old - pat) == HBLK-1.

// ---- K1: per-block LDS histogram + last-arriving-block top-20% selection ---
// NO device-scope atomics on the histogram (they were the 45us wall: 262k RMWs
// at the memory-side coherent point, ~183 GB/s). LDS atomics + plain stores.
__global__ __launch_bounds__(HTHR) void hist_select_kernel(
        const float* __restrict__ hm,
        unsigned long long* __restrict__ hist,
        const unsigned* __restrict__ sent,
        unsigned* __restrict__ bar,
        float* __restrict__ max20) {
    __shared__ unsigned long long lh[NBINS];   // 64 KB private histogram
    __shared__ unsigned sc[HTHR];
    __shared__ double   ss[HTHR];

    const int t = threadIdx.x;
    const int tid = blockIdx.x * HTHR + t;     // 32768 threads

    for (int i = t; i < NBINS; i += HTHR) lh[i] = 0ull;
    __syncthreads();

    // 8 values per thread (2 x float4, coalesced)
    const float4* h4 = (const float4*)hm;
    float4 va = h4[2 * tid];
    float4 vb = h4[2 * tid + 1];
    float vv[8] = {va.x, va.y, va.z, va.w, vb.x, vb.y, vb.z, vb.w};
#pragma unroll
    for (int q = 0; q < 8; ++q) {
        float v = vv[q];
        if (v > 0.001f) {
            int b = (int)(v * (float)NBINS);
            b = min(max(b, 0), NBINS - 1);
            unsigned long long pkt = (1ull << 44) |
                (unsigned long long)(unsigned)(v * 16777216.0f + 0.5f);
            atomicAdd(&lh[b], pkt);            // LDS atomic — stays on-CU
        }
    }
    __syncthreads();

    // flush private histogram slice: plain coalesced agent-scope stores (64 KB)
    for (int i = t; i < NBINS; i += HTHR)
        __hip_atomic_store(&hist[(size_t)blockIdx.x * NBINS + i], lh[i],
                           __ATOMIC_RELAXED, __HIP_MEMORY_SCOPE_AGENT);

    const unsigned pat = *sent;   // poison pattern (ws re-poisoned each replay)

    // arrival: __syncthreads drained our stores; release publishes them.
    __shared__ int s_last;
    __syncthreads();
    if (t == 0) {
        unsigned old = __hip_atomic_fetch_add(bar, 1u, __ATOMIC_ACQ_REL,
                                              __HIP_MEMORY_SCOPE_AGENT);
        s_last = ((old - pat) == (unsigned)(HBLK - 1)) ? 1 : 0;
    }
    __syncthreads();
    if (!s_last) return;

    // ---- selection (one block; 1024 threads, 8 descending bins each) ------
    const unsigned long long M44 = (1ull << 44) - 1;
    // thread t owns bins [lo, lo+8): t=0 owns the TOP bins.
    const int lo = NBINS - BINS_PER_T * (t + 1);

    unsigned c = 0;
    double   s = 0.0;
#pragma unroll
    for (int j = 0; j < BINS_PER_T; ++j) {
        int b = lo + j;
        unsigned long long m = 0ull;   // merged packet; fields can't overflow
#pragma unroll
        for (int p = 0; p < HBLK; ++p)
            m += __hip_atomic_load(&hist[(size_t)p * NBINS + b],
                                   __ATOMIC_RELAXED, __HIP_MEMORY_SCOPE_AGENT);
        lh[b] = m;                     // stash merged packet for the fine walk
        c += (unsigned)(m >> 44);
        s += (double)(m & M44) * (1.0 / 16777216.0);
    }
    sc[t] = c; ss[t] = s;
    __syncthreads();
    for (int off = 1; off < HTHR; off <<= 1) {
        unsigned ca = (t >= off) ? sc[t - off] : 0u;
        double   sa = (t >= off) ? ss[t - off] : 0.0;
        __syncthreads();
        sc[t] += ca; ss[t] += sa;
        __syncthreads();
    }
    unsigned incl_c = sc[t];
    double   incl_s = ss[t];
    unsigned excl_c = incl_c - c;
    double   excl_s = incl_s - s;

    unsigned C = sc[HTHR - 1];              // total valid count
    int k = (int)ceilf((float)C * 0.2f);    // replicate jnp f32 arithmetic
    if (k <= 0) {
        if (t == 0) *max20 = 0.0f;
        return;
    }
    // exactly one thread's range straddles the k-th value: LDS fine walk, descending
    if (excl_c < (unsigned)k && incl_c >= (unsigned)k) {
        unsigned cum = excl_c;
        double sacc = excl_s;
        for (int j = BINS_PER_T - 1; j >= 0; --j) {
            unsigned long long m = lh[lo + j];
            unsigned cb = (unsigned)(m >> 44);
            double sb = (double)(m & M44) * (1.0 / 16777216.0);
            if (cum + cb >= (unsigned)k) {
                unsigned r = (unsigned)k - cum;
                double partial = cb ? sb * ((double)r / (double)cb) : 0.0;
                *max20 = (float)((sacc + partial) / (double)k);
                break;
            }
            cum += cb;
            sacc += sb;
        }
    }
}

// ---- K2: refine + junctions + full line_map --------------------------------
// Non-center patch offsets, ascending radius (28 entries; center handled first).
__global__ __launch_bounds__(CTHR) void main_kernel(const float* __restrict__ junc,
                                                    const float* __restrict__ hm,
                                                    const float* __restrict__ max20p,
                                                    float* __restrict__ out_lm,
                                                    float* __restrict__ out_junc,
                                                    float* __restrict__ out_hm) {
    constexpr int OH[28] = { 0, 0, 1,-1,  1, 1,-1,-1,  0, 0, 2,-2,
                             1, 1,-1,-1, 2, 2,-2,-2,  2, 2,-2,-2,  0, 0, 3,-3};
    constexpr int OW[28] = { 1,-1, 0, 0,  1,-1, 1,-1,  2,-2, 0, 0,
                             2,-2, 2,-2, 1,-1, 1,-1,  2,-2, 2,-2,  3,-3, 0, 0};

    __shared__ float sj[2 * NJ];
    const int tid  = blockIdx.x * CTHR + threadIdx.x;
    const int lane = threadIdx.x & 63;
    const float m = *max20p;

    for (int i = threadIdx.x; i < 2 * NJ; i += CTHR) sj[i] = junc[i];

    // refined heatmap: first 65536 threads, one float4 each
    if (tid < HH * WW / 4) {
        const float4* h4 = (const float4*)hm;
        float4* o4 = (float4*)out_hm;
        float4 v = h4[tid];
        float4 r;
        r.x = fminf(fmaxf(v.x / m, 0.0f), 1.0f);
        r.y = fminf(fmaxf(v.y / m, 0.0f), 1.0f);
        r.z = fminf(fmaxf(v.z / m, 0.0f), 1.0f);
        r.w = fminf(fmaxf(v.w / m, 0.0f), 1.0f);
        o4[tid] = r;
    }
    if (tid < 2 * NJ) out_junc[tid] = junc[tid];
    if (tid < NJ) out_lm[tid * (NJ + 1)] = 0.0f;   // diagonal
    __syncthreads();

    // each lane caches 4 junctions in registers for the keep-test (reused all pairs)
    float jh[4], jw[4];
    int   jn[4];
#pragma unroll
    for (int q = 0; q < 4; ++q) {
        int n = lane + 64 * q;
        bool ok = n < NJ;
        jn[q] = n;
        jh[q] = ok ? sj[2 * n]     : 1.0e9f;   // sentinel: never on any segment
        jw[q] = ok ? sj[2 * n + 1] : 1.0e9f;
    }

    const int wave = tid >> 6;
    for (int mm = wave; mm < NPAIR; mm += CWAVES) {
        // decode triangular index: base(i) = i*(499-i)/2 (fixups make exact)
        int i = (int)((499.0f - sqrtf(249001.0f - 8.0f * (float)mm)) * 0.5f);
        if (i < 0) i = 0;
        if (i > 248) i = 248;
        while ((i + 1) * (499 - (i + 1)) / 2 <= mm) ++i;
        while (i * (499 - i) / 2 > mm) --i;
        int j = i + 1 + (mm - i * (499 - i) / 2);

        float sh = sj[2 * i], sw = sj[2 * i + 1];
        float eh = sj[2 * j], ew = sj[2 * j + 1];
        float dh = eh - sh, dw = ew - sw;
        float L2 = dh * dh + dw * dw;

        // keep-test: pure register VALU, no loads
        bool sup = false;
#pragma unroll
        for (int q = 0; q < 4; ++q) {
            float vh = jh[q] - sh;
            float vw = jw[q] - sw;
            float dot = vh * dh + vw * dw;
            float dist2 = (vh * vh + vw * vw) - (dot * dot) / L2;
            bool on = (dot >= 0.0f) && (dot <= L2) && (dist2 <= 9.0f)
                      && (jn[q] != i) && (jn[q] != j);
            sup = sup || on;
        }
        bool det = false;
        if (!__any(sup)) {
            float t = (float)lane / 63.0f;
            float ch = fminf(fmaxf(sh * t + eh * (1.0f - t), 0.0f), (float)(HH - 1));
            float cw = fminf(fmaxf(sw * t + ew * (1.0f - t), 0.0f), (float)(WW - 1));
            float rh = rintf(ch), rw = rintf(cw);
            float fh = ch - rh, fw = cw - rw;
            float L = sqrtf(L2);
            float nl = L / 724.07734f;
            float th = 0.70710678f + 2.0f * nl;
            float th2 = th * th;

            int crh = (int)rh, crw = (int)rw;
            // center point: always inside the mask (dist=hypot(fh,fw) <= 0.707 < th)
            float v0 = hm[(crh << 9) + crw];
            bool need = !(v0 / m > 0.5f);       // identical to ref clip(v/m)>0.5

            if (__any(need)) {
                // guarded independent loads: only unresolved lanes with a
                // mask-valid point issue memory traffic (TA lines ∝ active lanes)
                float vv[28];
#pragma unroll
                for (int p = 0; p < 28; ++p) {
                    vv[p] = 0.0f;
                    float ddh = fh - (float)OH[p];
                    float ddw = fw - (float)OW[p];
                    if (need && (ddh * ddh + ddw * ddw) < th2) {
                        int ph = min(max(crh + OH[p], 0), HH - 1);
                        int pw = min(max(crw + OW[p], 0), WW - 1);
                        vv[p] = hm[(ph << 9) + pw];
                    }
                }
                float best = 0.0f;
#pragma unroll
                for (int p = 0; p < 28; ++p) best = fmaxf(best, vv[p]);
                if (best / m > 0.5f) need = false;   // max commutes with monotone v/m
                det = !__any(need);
            } else {
                det = true;
            }
        }
        if (lane == 0) {
            float val = det ? 1.0f : 0.0f;
            out_lm[i * NJ + j] = val;
            out_lm[j * NJ + i] = val;
        }
    }
}

extern "C" void kernel_launch(void* const* d_in, const int* in_sizes, int n_in,
                              void* d_out, int out_size, void* d_ws, size_t ws_size,
                              hipStream_t stream) {
    const float* junc = (const float*)d_in[0];   // [250,2]
    const float* hm   = (const float*)d_in[1];   // [512,512]
    float* out = (float*)d_out;
    float* out_lm   = out;                      // 62500 floats (0.0/1.0)
    float* out_junc = out + NJ * NJ;            // 500
    float* out_hm   = out + NJ * NJ + 2 * NJ;   // 262144

    unsigned long long* hist = (unsigned long long*)d_ws;  // 2 MB, fully rewritten
    float*    max20 = (float*)((char*)d_ws + (size_t)HBLK * NBINS * 8);
    unsigned* sent  = (unsigned*)((char*)d_ws + (size_t)HBLK * NBINS * 8 + 64);  // never written
    unsigned* bar   = (unsigned*)((char*)d_ws + (size_t)HBLK * NBINS * 8 + 128); // arrival counter

    hist_select_kernel<<<HBLK, HTHR, 0, stream>>>(hm, hist, sent, bar, max20);
    main_kernel<<<CBLK, CTHR, 0, stream>>>(junc, hm, max20, out_lm, out_junc, out_hm);
}

// Round 6
// 93.178 us; speedup vs baseline: 1.5804x; 1.5804x over previous
//
#include <hip/hip_runtime.h>
#include <hip/hip_bf16.h>

#define HH 512
#define WW 512
#define NJ 250
#define NBINS 8192
#define NPAIR 31125   // 250*249/2

#define HBLK 4
#define HTHR 1024
#define BINS_PER_T (NBINS / HTHR)   // 8
#define CBLK 2048
#define CTHR 256
#define CWAVES (CBLK * CTHR / 64)

// ws layout:
//   u64 hist[HBLK][NBINS]   @ 0      (256 KB) — fully overwritten each launch
//                                     (plain agent stores), NO poison arithmetic
//   f32 max20               @ 256 KB
//   u32 sentinel            @ 256 KB + 64   <- NEVER written: holds poison pattern
//   u32 barrier             @ 256 KB + 128  <- fetch_add'ed; poison-initialized
// packet = (1<<44) | round(v*2^24): cnt in [63:44], fixed-point sum in [43:0].
// merged-over-4-replicas packet fits: cnt <= 2^18 < 2^20, sum <= 2^42 < 2^44.
// barrier counter: init == poison u32; "last" block sees (old - pat) == HBLK-1.
//
// Sizing rationale (R5 post-mortem): BOTH the per-block hm load and the last-
// block merge run at the per-CU latency-bound streaming rate (~26-47 GB/s).
// Cost ~ 1MB/HBLK (load) + (HBLK-1)*64KB (merge) -> minimized at HBLK=4.
// R5 (HBLK=32) paid 2 MB single-CU merge = 45-60us. R4 (device atomics) = 46us.

// ---- K1: per-block LDS histogram + last-arriving-block top-20% selection ---
__global__ __launch_bounds__(HTHR) void hist_select_kernel(
        const float* __restrict__ hm,
        unsigned long long* __restrict__ hist,
        const unsigned* __restrict__ sent,
        unsigned* __restrict__ bar,
        float* __restrict__ max20) {
    __shared__ unsigned long long lh[NBINS];   // 64 KB private histogram
    __shared__ unsigned sc[HTHR];
    __shared__ double   ss[HTHR];

    const int t  = threadIdx.x;
    const int bx = blockIdx.x;

    for (int i = t; i < NBINS; i += HTHR) lh[i] = 0ull;
    __syncthreads();

    // 64 values per thread (16 x float4, coalesced 16KB per iteration)
    const float4* h4 = (const float4*)hm;
#pragma unroll
    for (int g = 0; g < 16; ++g) {
        float4 v4 = h4[bx * 16384 + g * HTHR + t];
        float vv[4] = {v4.x, v4.y, v4.z, v4.w};
#pragma unroll
        for (int q = 0; q < 4; ++q) {
            float v = vv[q];
            if (v > 0.001f) {
                int b = (int)(v * (float)NBINS);
                b = min(max(b, 0), NBINS - 1);
                unsigned long long pkt = (1ull << 44) |
                    (unsigned long long)(unsigned)(v * 16777216.0f + 0.5f);
                atomicAdd(&lh[b], pkt);        // LDS atomic — stays on-CU
            }
        }
    }
    __syncthreads();

    // flush private histogram: plain coalesced agent-scope stores (64 KB)
    for (int i = t; i < NBINS; i += HTHR)
        __hip_atomic_store(&hist[(size_t)bx * NBINS + i], lh[i],
                           __ATOMIC_RELAXED, __HIP_MEMORY_SCOPE_AGENT);

    const unsigned pat = *sent;   // poison pattern (ws re-poisoned each replay)

    // arrival: release publishes our stores; last arriver acquires everyone's.
    __shared__ int s_last;
    __syncthreads();
    if (t == 0) {
        unsigned old = __hip_atomic_fetch_add(bar, 1u, __ATOMIC_ACQ_REL,
                                              __HIP_MEMORY_SCOPE_AGENT);
        s_last = ((old - pat) == (unsigned)(HBLK - 1)) ? 1 : 0;
    }
    __syncthreads();
    if (!s_last) return;

    // ---- selection (one block; 1024 threads, 8 descending bins each) ------
    // Own replica is still in LDS: merge only the 3 foreign replicas (192 KB).
    const unsigned long long M44 = (1ull << 44) - 1;
    const int lo = NBINS - BINS_PER_T * (t + 1);   // t=0 owns the TOP bins

    unsigned c = 0;
    double   s = 0.0;
#pragma unroll
    for (int j = 0; j < BINS_PER_T; ++j) {
        int b = lo + j;
        unsigned long long m = lh[b];              // own replica
#pragma unroll
        for (int p = 0; p < HBLK; ++p) {
            if (p == bx) continue;
            m += __hip_atomic_load(&hist[(size_t)p * NBINS + b],
                                   __ATOMIC_RELAXED, __HIP_MEMORY_SCOPE_AGENT);
        }
        lh[b] = m;                     // stash merged packet for the fine walk
        c += (unsigned)(m >> 44);
        s += (double)(m & M44) * (1.0 / 16777216.0);
    }
    sc[t] = c; ss[t] = s;
    __syncthreads();
    for (int off = 1; off < HTHR; off <<= 1) {
        unsigned ca = (t >= off) ? sc[t - off] : 0u;
        double   sa = (t >= off) ? ss[t - off] : 0.0;
        __syncthreads();
        sc[t] += ca; ss[t] += sa;
        __syncthreads();
    }
    unsigned incl_c = sc[t];
    double   incl_s = ss[t];
    unsigned excl_c = incl_c - c;
    double   excl_s = incl_s - s;

    unsigned C = sc[HTHR - 1];              // total valid count
    int k = (int)ceilf((float)C * 0.2f);    // replicate jnp f32 arithmetic
    if (k <= 0) {
        if (t == 0) *max20 = 0.0f;
        return;
    }
    // exactly one thread's range straddles the k-th value: LDS fine walk, descending
    if (excl_c < (unsigned)k && incl_c >= (unsigned)k) {
        unsigned cum = excl_c;
        double sacc = excl_s;
        for (int j = BINS_PER_T - 1; j >= 0; --j) {
            unsigned long long m = lh[lo + j];
            unsigned cb = (unsigned)(m >> 44);
            double sb = (double)(m & M44) * (1.0 / 16777216.0);
            if (cum + cb >= (unsigned)k) {
                unsigned r = (unsigned)k - cum;
                double partial = cb ? sb * ((double)r / (double)cb) : 0.0;
                *max20 = (float)((sacc + partial) / (double)k);
                break;
            }
            cum += cb;
            sacc += sb;
        }
    }
}

// ---- K2: refine + junctions + full line_map --------------------------------
// Non-center patch offsets, ascending radius (28 entries; center handled first).
__global__ __launch_bounds__(CTHR) void main_kernel(const float* __restrict__ junc,
                                                    const float* __restrict__ hm,
                                                    const float* __restrict__ max20p,
                                                    float* __restrict__ out_lm,
                                                    float* __restrict__ out_junc,
                                                    float* __restrict__ out_hm) {
    constexpr int OH[28] = { 0, 0, 1,-1,  1, 1,-1,-1,  0, 0, 2,-2,
                             1, 1,-1,-1, 2, 2,-2,-2,  2, 2,-2,-2,  0, 0, 3,-3};
    constexpr int OW[28] = { 1,-1, 0, 0,  1,-1, 1,-1,  2,-2, 0, 0,
                             2,-2, 2,-2, 1,-1, 1,-1,  2,-2, 2,-2,  3,-3, 0, 0};

    __shared__ float sj[2 * NJ];
    const int tid  = blockIdx.x * CTHR + threadIdx.x;
    const int lane = threadIdx.x & 63;
    const float m = *max20p;

    for (int i = threadIdx.x; i < 2 * NJ; i += CTHR) sj[i] = junc[i];

    // refined heatmap: first 65536 threads, one float4 each
    if (tid < HH * WW / 4) {
        const float4* h4 = (const float4*)hm;
        float4* o4 = (float4*)out_hm;
        float4 v = h4[tid];
        float4 r;
        r.x = fminf(fmaxf(v.x / m, 0.0f), 1.0f);
        r.y = fminf(fmaxf(v.y / m, 0.0f), 1.0f);
        r.z = fminf(fmaxf(v.z / m, 0.0f), 1.0f);
        r.w = fminf(fmaxf(v.w / m, 0.0f), 1.0f);
        o4[tid] = r;
    }
    if (tid < 2 * NJ) out_junc[tid] = junc[tid];
    if (tid < NJ) out_lm[tid * (NJ + 1)] = 0.0f;   // diagonal
    __syncthreads();

    // each lane caches 4 junctions in registers for the keep-test (reused all pairs)
    float jh[4], jw[4];
    int   jn[4];
#pragma unroll
    for (int q = 0; q < 4; ++q) {
        int n = lane + 64 * q;
        bool ok = n < NJ;
        jn[q] = n;
        jh[q] = ok ? sj[2 * n]     : 1.0e9f;   // sentinel: never on any segment
        jw[q] = ok ? sj[2 * n + 1] : 1.0e9f;
    }

    const int wave = tid >> 6;
    for (int mm = wave; mm < NPAIR; mm += CWAVES) {
        // decode triangular index: base(i) = i*(499-i)/2 (fixups make exact)
        int i = (int)((499.0f - sqrtf(249001.0f - 8.0f * (float)mm)) * 0.5f);
        if (i < 0) i = 0;
        if (i > 248) i = 248;
        while ((i + 1) * (499 - (i + 1)) / 2 <= mm) ++i;
        while (i * (499 - i) / 2 > mm) --i;
        int j = i + 1 + (mm - i * (499 - i) / 2);

        float sh = sj[2 * i], sw = sj[2 * i + 1];
        float eh = sj[2 * j], ew = sj[2 * j + 1];
        float dh = eh - sh, dw = ew - sw;
        float L2 = dh * dh + dw * dw;

        // keep-test: pure register VALU, no loads
        bool sup = false;
#pragma unroll
        for (int q = 0; q < 4; ++q) {
            float vh = jh[q] - sh;
            float vw = jw[q] - sw;
            float dot = vh * dh + vw * dw;
            float dist2 = (vh * vh + vw * vw) - (dot * dot) / L2;
            bool on = (dot >= 0.0f) && (dot <= L2) && (dist2 <= 9.0f)
                      && (jn[q] != i) && (jn[q] != j);
            sup = sup || on;
        }
        bool det = false;
        if (!__any(sup)) {
            float t = (float)lane / 63.0f;
            float ch = fminf(fmaxf(sh * t + eh * (1.0f - t), 0.0f), (float)(HH - 1));
            float cw = fminf(fmaxf(sw * t + ew * (1.0f - t), 0.0f), (float)(WW - 1));
            float rh = rintf(ch), rw = rintf(cw);
            float fh = ch - rh, fw = cw - rw;
            float L = sqrtf(L2);
            float nl = L / 724.07734f;
            float th = 0.70710678f + 2.0f * nl;
            float th2 = th * th;

            int crh = (int)rh, crw = (int)rw;
            // center point: always inside the mask (dist=hypot(fh,fw) <= 0.707 < th)
            float v0 = hm[(crh << 9) + crw];
            bool need = !(v0 / m > 0.5f);       // identical to ref clip(v/m)>0.5

            if (__any(need)) {
                // guarded independent loads: only unresolved lanes with a
                // mask-valid point issue memory traffic (TA lines ∝ active lanes)
                float vv[28];
#pragma unroll
                for (int p = 0; p < 28; ++p) {
                    vv[p] = 0.0f;
                    float ddh = fh - (float)OH[p];
                    float ddw = fw - (float)OW[p];
                    if (need && (ddh * ddh + ddw * ddw) < th2) {
                        int ph = min(max(crh + OH[p], 0), HH - 1);
                        int pw = min(max(crw + OW[p], 0), WW - 1);
                        vv[p] = hm[(ph << 9) + pw];
                    }
                }
                float best = 0.0f;
#pragma unroll
                for (int p = 0; p < 28; ++p) best = fmaxf(best, vv[p]);
                if (best / m > 0.5f) need = false;   // max commutes with monotone v/m
                det = !__any(need);
            } else {
                det = true;
            }
        }
        if (lane == 0) {
            float val = det ? 1.0f : 0.0f;
            out_lm[i * NJ + j] = val;
            out_lm[j * NJ + i] = val;
        }
    }
}

extern "C" void kernel_launch(void* const* d_in, const int* in_sizes, int n_in,
                              void* d_out, int out_size, void* d_ws, size_t ws_size,
                              hipStream_t stream) {
    const float* junc = (const float*)d_in[0];   // [250,2]
    const float* hm   = (const float*)d_in[1];   // [512,512]
    float* out = (float*)d_out;
    float* out_lm   = out;                      // 62500 floats (0.0/1.0)
    float* out_junc = out + NJ * NJ;            // 500
    float* out_hm   = out + NJ * NJ + 2 * NJ;   // 262144

    unsigned long long* hist = (unsigned long long*)d_ws;  // 256 KB, fully rewritten
    float*    max20 = (float*)((char*)d_ws + (size_t)HBLK * NBINS * 8);
    unsigned* sent  = (unsigned*)((char*)d_ws + (size_t)HBLK * NBINS * 8 + 64);  // never written
    unsigned* bar   = (unsigned*)((char*)d_ws + (size_t)HBLK * NBINS * 8 + 128); // arrival counter

    hist_select_kernel<<<HBLK, HTHR, 0, stream>>>(hm, hist, sent, bar, max20);
    main_kernel<<<CBLK, CTHR, 0, stream>>>(junc, hm, max20, out_lm, out_junc, out_hm);
}